// Round 2
// baseline (355.752 us; speedup 1.0000x reference)
//
#include <hip/hip_runtime.h>

typedef __bf16 bf16;
typedef __bf16 bf16x8 __attribute__((ext_vector_type(8)));
typedef __bf16 bf16x4 __attribute__((ext_vector_type(4)));
typedef float f32x4 __attribute__((ext_vector_type(4)));

#define N_DIM 196
#define C_DIM 768
#define B_DIM 256
#define KSTEPS 7           // 7*32 = 224 padded contraction length
#define MT1 14             // GEMM1 M-tiles (freq k padded to 224)
#define MT2 13             // GEMM2 M-tiles (n padded to 208)
#define CT 64              // channels per block
#define NTILES 12          // C_DIM / CT

#define D2F_ELEMS (MT1 * KSTEPS * 512)          // 50176 bf16
#define EF_ELEMS  (MT2 * KSTEPS * 512)          // 46592 bf16
#define WF_ELEMS  (NTILES * MT1 * 4 * 64 * 4)   // 172032 fp32

// LDS: 64 rows (channels) x 256 elems (m / k, padded), bf16, XOR-swizzled on
// 16B granules. key = ((row>>2)&7) ^ ((row&1)<<2):
//  - staging b64 writes (rows = 4j+k, k fixed per instr): key spans 8 via j -> 4 dw/bank (conflict-free min)
//  - b128 frag reads (rows = ct*16+ln15): key spans 8 via (a, b&1) -> uniform 8 dw/bank (b128 optimum)
__device__ __forceinline__ int swz(int row, int off) {
    return row * 256 + ((((off >> 3) ^ ((row >> 2) & 7) ^ ((row & 1) << 2)) << 3) | (off & 7));
}

// Precompute DCT matrices in MFMA A-fragment lane order, and the weight in
// epilogue lane order (coalesced float4 per lane).
__global__ void init_mats(const float* __restrict__ wgt,
                          bf16* __restrict__ d2f, bf16* __restrict__ ef,
                          float* __restrict__ wf) {
    int idx = blockIdx.x * 256 + threadIdx.x;
    const float PI = 3.14159265358979323846f;
    if (idx < D2F_ELEMS) {
        int j    = idx & 7;
        int lane = (idx >> 3) & 63;
        int rest = idx >> 9;
        int ks = rest % KSTEPS;
        int mt = rest / KSTEPS;
        int row = mt * 16 + (lane & 15);         // output freq k
        int col = ks * 32 + (lane >> 4) * 8 + j; // spatial m
        float v = 0.0f;
        if (row < N_DIM && col < N_DIM) {
            int t = ((2 * col + 1) * row) % (4 * N_DIM);
            v = 2.0f * cosf(PI * (float)t / (float)(2 * N_DIM));
        }
        d2f[idx] = (bf16)v;
        return;
    }
    idx -= D2F_ELEMS;
    if (idx < EF_ELEMS) {
        int j    = idx & 7;
        int lane = (idx >> 3) & 63;
        int rest = idx >> 9;
        int ks = rest % KSTEPS;
        int mt = rest / KSTEPS;
        int row = mt * 16 + (lane & 15);         // output n
        int col = ks * 32 + (lane >> 4) * 8 + j; // freq k
        float v = 0.0f;
        if (row < N_DIM && col < N_DIM) {
            if (col == 0) v = 1.0f / (float)(2 * N_DIM);
            else {
                int t = ((2 * row + 1) * col) % (4 * N_DIM);
                v = cosf(PI * (float)t / (float)(2 * N_DIM)) / (float)N_DIM;
            }
        }
        ef[idx] = (bf16)v;
        return;
    }
    idx -= EF_ELEMS;
    if (idx < WF_ELEMS) {
        // layout: (((ctile*MT1 + mt)*4 + ct)*64 + lane)*4 + r
        int r    = idx & 3;
        int lane = (idx >> 2) & 63;
        int rest = idx >> 8;
        int ct    = rest & 3;
        int rest2 = rest >> 2;
        int mt    = rest2 % MT1;
        int ctile = rest2 / MT1;
        int c = ctile * CT + ct * 16 + (lane & 15);
        int k = mt * 16 + ((lane >> 4) & 3) * 4 + r;
        wf[idx] = (k < N_DIM) ? wgt[(size_t)c * N_DIM + k] : 0.0f;
    }
}

// One block = one (batch, 64-channel) tile. T1 = D2@x (MFMA), *w -> bf16 back
// into same LDS, y = E@T1w (MFMA), store fp32.
__global__ __launch_bounds__(256, 5) void dct_fused(
        const float* __restrict__ x, const float* __restrict__ wf,
        const bf16* __restrict__ d2f, const bf16* __restrict__ ef,
        float* __restrict__ out) {
    __shared__ bf16 lds[CT * 256];     // 32 KiB -> 5 blocks/CU

    const int ctile = blockIdx.x;
    const int b  = blockIdx.y;
    const int c0 = ctile * CT;
    const int t  = threadIdx.x;
    const int wave = t >> 6;
    const int lane = t & 63;
    const int ln15 = lane & 15;
    const int q    = lane >> 4;        // quad 0..3

    // ---- stage x[b, :, c0:c0+64] -> lds[c][m] (bf16, swizzled)
    {
        const int c4 = (t & 15) * 4;   // 4 channels per thread
        const int mq = t >> 4;         // m-quad slot 0..15
#pragma unroll
        for (int i = 0; i < 4; ++i) {
            int quad = i * 16 + mq;    // m-quad 0..63; data quads 0..48
            if (quad > 55) continue;   // m>=224: never read
            int m0 = quad * 4;
            float4 v0, v1, v2, v3;
            if (quad <= 48) {
                const float* p = x + ((size_t)b * N_DIM + m0) * C_DIM + c0 + c4;
                v0 = *(const float4*)(p);
                v1 = *(const float4*)(p + C_DIM);
                v2 = *(const float4*)(p + 2 * C_DIM);
                v3 = *(const float4*)(p + 3 * C_DIM);
            } else {                   // zero-pad m in [196,224)
                v0 = v1 = v2 = v3 = make_float4(0.f, 0.f, 0.f, 0.f);
            }
            const float rx[4] = {v0.x, v1.x, v2.x, v3.x};
            const float ry[4] = {v0.y, v1.y, v2.y, v3.y};
            const float rz[4] = {v0.z, v1.z, v2.z, v3.z};
            const float rw[4] = {v0.w, v1.w, v2.w, v3.w};
            const float* rows[4] = {rx, ry, rz, rw};
#pragma unroll
            for (int k = 0; k < 4; ++k) {
                bf16x4 pv;
                pv[0] = (bf16)rows[k][0];
                pv[1] = (bf16)rows[k][1];
                pv[2] = (bf16)rows[k][2];
                pv[3] = (bf16)rows[k][3];
                *(bf16x4*)(lds + swz(c4 + k, m0)) = pv;
            }
        }
    }
    __syncthreads();

    // ---- GEMM1: T1[k, c] = sum_m D2[k,m] * x[m,c]
    f32x4 acc[4][4] = {};
    for (int ks = 0; ks < KSTEPS; ++ks) {
        bf16x8 bfr[4];
#pragma unroll
        for (int ct = 0; ct < 4; ++ct)
            bfr[ct] = *(const bf16x8*)(lds + swz(ct * 16 + ln15, ks * 32 + q * 8));
#pragma unroll
        for (int ml = 0; ml < 4; ++ml) {
            int mt = wave + 4 * ml;
            if (mt < MT1) {
                bf16x8 afr = *(const bf16x8*)(d2f + ((size_t)(mt * KSTEPS + ks) * 64 + lane) * 8);
#pragma unroll
                for (int ct = 0; ct < 4; ++ct)
                    acc[ml][ct] = __builtin_amdgcn_mfma_f32_16x16x32_bf16(afr, bfr[ct], acc[ml][ct], 0, 0, 0);
            }
        }
    }
    __syncthreads();

    // ---- epilogue: T1w[k,c] = T1[k,c]*w[c,k] -> bf16 back into LDS
    //      (wf pre-laid-out: coalesced float4 per lane; zero for k>=196)
#pragma unroll
    for (int ml = 0; ml < 4; ++ml) {
        int mt = wave + 4 * ml;
        if (mt >= MT1) continue;
        int kb = mt * 16 + q * 4;
#pragma unroll
        for (int ct = 0; ct < 4; ++ct) {
            int cc = ct * 16 + ln15;
            float4 wv = *(const float4*)(wf + ((size_t)((ctile * MT1 + mt) * 4 + ct) * 64 + lane) * 4);
            bf16x4 pv;
            pv[0] = (bf16)(acc[ml][ct][0] * wv.x);
            pv[1] = (bf16)(acc[ml][ct][1] * wv.y);
            pv[2] = (bf16)(acc[ml][ct][2] * wv.z);
            pv[3] = (bf16)(acc[ml][ct][3] * wv.w);
            *(bf16x4*)(lds + swz(cc, kb)) = pv;
        }
    }
    __syncthreads();

    // ---- GEMM2: y[n, c] = sum_k E[n,k] * T1w[k,c]
    f32x4 acc2[4][4] = {};
    for (int ks = 0; ks < KSTEPS; ++ks) {
        bf16x8 bfr[4];
#pragma unroll
        for (int ct = 0; ct < 4; ++ct)
            bfr[ct] = *(const bf16x8*)(lds + swz(ct * 16 + ln15, ks * 32 + q * 8));
#pragma unroll
        for (int ml = 0; ml < 4; ++ml) {
            int mt = wave + 4 * ml;
            if (mt < MT2) {
                bf16x8 afr = *(const bf16x8*)(ef + ((size_t)(mt * KSTEPS + ks) * 64 + lane) * 8);
#pragma unroll
                for (int ct = 0; ct < 4; ++ct)
                    acc2[ml][ct] = __builtin_amdgcn_mfma_f32_16x16x32_bf16(afr, bfr[ct], acc2[ml][ct], 0, 0, 0);
            }
        }
    }

    // ---- store y[b, n, c] fp32
#pragma unroll
    for (int ml = 0; ml < 4; ++ml) {
        int mt = wave + 4 * ml;
        if (mt >= MT2) continue;
#pragma unroll
        for (int ct = 0; ct < 4; ++ct) {
            int cc = ct * 16 + ln15;
#pragma unroll
            for (int r = 0; r < 4; ++r) {
                int n = mt * 16 + q * 4 + r;
                if (n < N_DIM)
                    out[((size_t)b * N_DIM + n) * C_DIM + c0 + cc] = acc2[ml][ct][r];
            }
        }
    }
}

extern "C" void kernel_launch(void* const* d_in, const int* in_sizes, int n_in,
                              void* d_out, int out_size, void* d_ws, size_t ws_size,
                              hipStream_t stream) {
    const float* x   = (const float*)d_in[0];   // [256,196,768] fp32
    const float* wgt = (const float*)d_in[1];   // [768,196] fp32
    float* out = (float*)d_out;                 // [256,196,768] fp32

    bf16* d2f  = (bf16*)d_ws;                   // 100,352 B
    bf16* ef   = d2f + D2F_ELEMS;               // 93,184 B
    float* wf  = (float*)(ef + EF_ELEMS);       // 688,128 B  (total ~862 KB)

    int tot = D2F_ELEMS + EF_ELEMS + WF_ELEMS;
    init_mats<<<(tot + 255) / 256, 256, 0, stream>>>(wgt, d2f, ef, wf);

    dim3 grid(NTILES, B_DIM);                   // 12 x 256 = 3072 blocks
    dct_fused<<<grid, 256, 0, stream>>>(x, wf, d2f, ef, out);
}